// Round 8
// baseline (589.572 us; speedup 1.0000x reference)
//
#include <hip/hip_runtime.h>

typedef unsigned short u16;
typedef __attribute__((ext_vector_type(8))) short short8;
typedef __attribute__((ext_vector_type(4))) float f32x4;
typedef __attribute__((ext_vector_type(4))) unsigned uint4v;

__device__ __forceinline__ float bf2f(u16 u){
  unsigned v = ((unsigned)u) << 16;
  return __builtin_bit_cast(float, v);
}
__device__ __forceinline__ u16 f2bf(float f){
  unsigned u = __builtin_bit_cast(unsigned, f);
  u += 0x7fff + ((u >> 16) & 1);   // RNE
  return (u16)(u >> 16);
}
__device__ __forceinline__ unsigned packbf(float lo, float hi){
  return ((unsigned)f2bf(hi) << 16) | (unsigned)f2bf(lo);
}
__device__ __forceinline__ void async16(const void* g, void* l){
  __builtin_amdgcn_global_load_lds((const __attribute__((address_space(1))) void*)g,
                                   (__attribute__((address_space(3))) void*)l, 16, 0, 0);
}
#define VMW(n) asm volatile("s_waitcnt vmcnt(" #n ")" ::: "memory")

// ---------------- ada partials ----------------
__global__ __launch_bounds__(256) void ada_partial(
    const float* __restrict__ c, const float* __restrict__ aw,
    float* __restrict__ part){
  int n  = blockIdx.x*256 + threadIdx.x;    // 24 x-blocks
  int b  = blockIdx.y;                      // 8
  int kc = blockIdx.z;                      // 8
  const float* cr  = c + b*1024 + kc*128;
  const float* awp = aw + (size_t)(kc*128)*6144 + n;
  float acc = 0.f;
#pragma unroll 8
  for (int k = 0; k < 128; ++k)
    acc += cr[k] * awp[(size_t)k*6144];
  part[(size_t)(kc*8 + b)*6144 + n] = acc;
}

// ---------------- ada = sum_kc part + ab ----------------
__global__ __launch_bounds__(256) void ada_reduce(
    const float* __restrict__ part, const float* __restrict__ ab,
    float* __restrict__ ada){
  int idx = blockIdx.x*256 + threadIdx.x;   // 192 blocks
  int n = idx % 6144;
  float acc = ab[n];
#pragma unroll
  for (int kc = 0; kc < 8; ++kc)
    acc += part[(size_t)kc*49152 + idx];
  ada[idx] = acc;
}

// ---------------- transpose + cast f32[K][N] -> bf16[N][K] ----------------
__global__ __launch_bounds__(256) void transpose_cast(
    const float* __restrict__ src, u16* __restrict__ dst, int K, int N){
  __shared__ float t[64][65];
  int n0 = blockIdx.x*64, k0 = blockIdx.y*64;
  int tid = threadIdx.x;
  int cc = tid & 63, r4 = tid >> 6;
#pragma unroll 4
  for (int it = 0; it < 16; ++it){
    int r = it*4 + r4;
    t[r][cc] = src[(size_t)(k0 + r)*N + n0 + cc];
  }
  __syncthreads();
#pragma unroll 4
  for (int it = 0; it < 16; ++it){
    int r = it*4 + r4;
    dst[(size_t)(n0 + r)*K + k0 + cc] = f2bf(t[cc][r]);
  }
}

// ---------------- LayerNorm + adaLN modulate -> bf16 ----------------
__global__ __launch_bounds__(256) void ln_mod(
    const float* __restrict__ x, u16* __restrict__ out,
    const float* __restrict__ w, const float* __restrict__ ada,
    int shift_off, int scale_off){
  int t = blockIdx.x, tid = threadIdx.x;
  const float* xr = x + (size_t)t*1024;
  float v[4]; float s = 0.f, ss = 0.f;
#pragma unroll
  for (int i = 0; i < 4; ++i){ v[i] = xr[tid + i*256]; s += v[i]; ss += v[i]*v[i]; }
  for (int d = 1; d < 64; d <<= 1){ s += __shfl_xor(s, d); ss += __shfl_xor(ss, d); }
  __shared__ float red[8];
  int wv = tid >> 6;
  if ((tid & 63) == 0){ red[wv] = s; red[4+wv] = ss; }
  __syncthreads();
  s = red[0]+red[1]+red[2]+red[3];
  ss = red[4]+red[5]+red[6]+red[7];
  float mu = s * (1.f/1024.f);
  float var = ss * (1.f/1024.f) - mu*mu;
  float rs = rsqrtf(var + 1e-5f);
  int b = t >> 10;
  const float* sh = ada + b*6144 + shift_off;
  const float* sc = ada + b*6144 + scale_off;
#pragma unroll
  for (int i = 0; i < 4; ++i){
    int cidx = tid + i*256;
    float hh = (v[i]-mu)*rs*w[cidx]*(1.f + sc[cidx]) + sh[cidx];
    out[(size_t)t*1024 + cidx] = f2bf(hh);
  }
}

// Epilogue shared by both GEMM variants.
template<int EPI>
__device__ __forceinline__ void gemm_epi(
    void* Cout, int m, int n, int N, int m_off, float v,
    const float* e0, const float* e1, const float* e2){
  if (EPI == 0){
    ((u16*)Cout)[(size_t)m*N + n] = f2bf(v);
  } else if (EPI == 1){
    const int b = (m + m_off) >> 10;
    float g = e1[b*6144 + 2048 + n];
    ((float*)Cout)[(size_t)m*N + n] = e0[(size_t)m*N + n] + g*v;
  } else if (EPI == 2){
    float xx = v + e0[n];
    // gelu(tanh approx) = x * sigmoid(1.595769122x + 0.0713548163x^3)
    float u = xx*(1.5957691216f + 0.07135481626f*xx*xx);
    ((u16*)Cout)[(size_t)m*N + n] = f2bf(xx / (1.f + __expf(-u)));
  } else {
    const int b = (m + m_off) >> 10;
    float g = e1[b*6144 + 5120 + n];
    ((float*)Cout)[(size_t)m*N + n] = e2[(size_t)m*N + n] + g*(v + e0[n]);
  }
}

// XCD-chunked bijective remap: HW assigns XCD = linear_bid % 8 (x-fastest).
// Give XCD g a contiguous y-band (ny/8 rows) x all x, so blocks sharing an
// A-row-panel are co-resident on ONE XCD (A fetched once per L2, not 8x).
// Requires gridDim.y % 8 == 0.
__device__ __forceinline__ void xcd_remap(int& bx, int& by){
  const int nx = gridDim.x;
  const int yb = gridDim.y >> 3;
  const int bid = blockIdx.y*nx + blockIdx.x;
  const int g = bid & 7, ii = bid >> 3;
  bx = ii % nx;
  by = g*yb + ii/nx;
}

// ---------------- GEMM 256x256, BK=32, 4-deep ring, counted vmcnt, swizzled LDS,
// ONE barrier per K-step. Hazard ledger:
//  - stage(t) writes buf[(t+3)&3], last read at step t-1 -> ordered by the
//    end-of-(t-1) barrier (all waves' reads complete before any wave enters t).
//  - reads of buf[t&3] need tile t landed: VMW(8) at end of t-1 waits the
//    oldest 4 of 12 outstanding loads = tile t; barrier publishes to all waves.
//  - within-wave ds_read -> MFMA ordering = compiler lgkmcnt.
// No inner barriers -> waves slip within a step, overlapping LDS/MFMA/stage pipes.
// NOTE: 256^2/8-wave tile needs ~170 VGPR -> do NOT set min-waves > 2
// (launch_bounds(512,4) caps VGPR at 128 and spills acc: round-6, 6x slowdown).
template<int EPI>
__global__ __launch_bounds__(512, 2) void gemm_bt(
    const u16* __restrict__ A, const u16* __restrict__ Bt,
    void* __restrict__ Cout, int M, int N, int K, int m_off,
    const float* __restrict__ e0, const float* __restrict__ e1,
    const float* __restrict__ e2){
  __shared__ u16 lds[65536];               // 128 KiB
  const int tid = threadIdx.x;
  const int wv = tid >> 6, lane = tid & 63;
  const int quad = lane >> 4, ln = lane & 15;
  const int wr = wv >> 2, wc = wv & 3;
  int bx, by; xcd_remap(bx, by);
  const int n0 = bx*256, m0 = by*256;
  const int nt = K >> 5;

  const int swslot = (lane & 3) ^ ((lane >> 3) & 3);
  const u16* Ap = A  + (size_t)(m0 + wv*16 + (lane>>2))*K + swslot*8;
  const u16* Bp = Bt + (size_t)(n0 + wv*16 + (lane>>2))*K + swslot*8;
  const size_t hstep = (size_t)128*K;
  u16* lw = lds + wv*512;                  // wave-uniform LDS slice base

  f32x4 acc[8][4] = {};

#pragma unroll
  for (int tau = 0; tau < 3; ++tau){
    u16* d = lw + tau*16384;
    async16(Ap + (size_t)tau*32,         d);
    async16(Ap + hstep + (size_t)tau*32, d + 4096);
    async16(Bp + (size_t)tau*32,         d + 8192);
    async16(Bp + hstep + (size_t)tau*32, d + 12288);
  }
  VMW(8);
  __builtin_amdgcn_s_barrier();

  const int rsw = (quad ^ ((ln >> 1) & 3))*8;
  const u16* Ar = lds + (wr*128 + ln)*32 + rsw;
  const u16* Br = lds + 8192 + (wc*64 + ln)*32 + rsw;

  for (int t = 0; t < nt; ++t){
    const int bo = (t & 3)*16384;
    short8 bfr[4], af[4];
#pragma unroll
    for (int j = 0; j < 4; ++j) bfr[j] = *(const short8*)(Br + bo + j*512);
#pragma unroll
    for (int i = 0; i < 4; ++i) af[i]  = *(const short8*)(Ar + bo + i*512);
    if (t + 3 < nt){
      u16* d = lw + ((t+3)&3)*16384;
      async16(Ap + (size_t)(t+3)*32,         d);
      async16(Ap + hstep + (size_t)(t+3)*32, d + 4096);
      async16(Bp + (size_t)(t+3)*32,         d + 8192);
      async16(Bp + hstep + (size_t)(t+3)*32, d + 12288);
    }
    __builtin_amdgcn_s_setprio(1);
#pragma unroll
    for (int i = 0; i < 4; ++i)
#pragma unroll
      for (int j = 0; j < 4; ++j)
        acc[i][j] = __builtin_amdgcn_mfma_f32_16x16x32_bf16(af[i], bfr[j], acc[i][j], 0, 0, 0);
#pragma unroll
    for (int i = 0; i < 4; ++i) af[i] = *(const short8*)(Ar + bo + 2048 + i*512);
#pragma unroll
    for (int i = 0; i < 4; ++i)
#pragma unroll
      for (int j = 0; j < 4; ++j)
        acc[4+i][j] = __builtin_amdgcn_mfma_f32_16x16x32_bf16(af[i], bfr[j], acc[4+i][j], 0, 0, 0);
    __builtin_amdgcn_s_setprio(0);
    if (t + 4 <= nt)      VMW(8);
    else if (t + 3 == nt) VMW(4);
    else if (t + 2 == nt) VMW(0);
    __builtin_amdgcn_s_barrier();
  }

  const int mB = m0 + wr*128 + quad*4;
  const int nB = n0 + wc*64 + ln;
#pragma unroll
  for (int i = 0; i < 8; ++i)
#pragma unroll
    for (int r = 0; r < 4; ++r)
#pragma unroll
      for (int j = 0; j < 4; ++j)
        gemm_epi<EPI>(Cout, mB + i*16 + r, nB + j*16, N, m_off, acc[i][j][r], e0, e1, e2);
}

// ---------------- GEMM 128x128, BK=32, 4-deep ring, counted vmcnt, swizzled LDS,
// ONE barrier per K-step (same hazard ledger as gemm_bt). launch_bounds(256,4):
// 4 blocks/CU (VGPR cap 128 > ~96 used; LDS 4x32 KiB = 128 <= 160).
template<int EPI>
__global__ __launch_bounds__(256, 4) void gemm_bt128(
    const u16* __restrict__ A, const u16* __restrict__ Bt,
    void* __restrict__ Cout, int M, int N, int K, int m_off,
    const float* __restrict__ e0, const float* __restrict__ e1,
    const float* __restrict__ e2){
  __shared__ u16 lds[32768];               // 32 KiB: 4 bufs x (A 128x32 + B 128x32)
  const int tid = threadIdx.x;
  const int wv = tid >> 6, lane = tid & 63;
  const int quad = lane >> 4, ln = lane & 15;
  const int wr = wv >> 1, wc = wv & 1;
  int bx, by; xcd_remap(bx, by);
  const int n0 = bx*128, m0 = by*128;
  const int nt = K >> 5;

  const int swslot = (lane & 3) ^ ((lane >> 3) & 3);
  const u16* Ap = A  + (size_t)(m0 + wv*16 + (lane>>2))*K + swslot*8;
  const u16* Bp = Bt + (size_t)(n0 + wv*16 + (lane>>2))*K + swslot*8;
  const size_t hstep = (size_t)64*K;
  u16* lw = lds + wv*512;

  f32x4 acc[4][4] = {};

#pragma unroll
  for (int tau = 0; tau < 3; ++tau){
    u16* d = lw + tau*8192;
    async16(Ap + (size_t)tau*32,         d);
    async16(Ap + hstep + (size_t)tau*32, d + 2048);
    async16(Bp + (size_t)tau*32,         d + 4096);
    async16(Bp + hstep + (size_t)tau*32, d + 6144);
  }
  VMW(8);
  __builtin_amdgcn_s_barrier();

  const int rsw = (quad ^ ((ln >> 1) & 3))*8;
  const u16* Ar = lds + (wr*64 + ln)*32 + rsw;
  const u16* Br = lds + 4096 + (wc*64 + ln)*32 + rsw;

  for (int t = 0; t < nt; ++t){
    const int bo = (t & 3)*8192;
    short8 bfr[4], af[2];
#pragma unroll
    for (int j = 0; j < 4; ++j) bfr[j] = *(const short8*)(Br + bo + j*512);
#pragma unroll
    for (int i = 0; i < 2; ++i) af[i]  = *(const short8*)(Ar + bo + i*512);
    if (t + 3 < nt){
      u16* d = lw + ((t+3)&3)*8192;
      async16(Ap + (size_t)(t+3)*32,         d);
      async16(Ap + hstep + (size_t)(t+3)*32, d + 2048);
      async16(Bp + (size_t)(t+3)*32,         d + 4096);
      async16(Bp + hstep + (size_t)(t+3)*32, d + 6144);
    }
    __builtin_amdgcn_s_setprio(1);
#pragma unroll
    for (int i = 0; i < 2; ++i)
#pragma unroll
      for (int j = 0; j < 4; ++j)
        acc[i][j] = __builtin_amdgcn_mfma_f32_16x16x32_bf16(af[i], bfr[j], acc[i][j], 0, 0, 0);
#pragma unroll
    for (int i = 0; i < 2; ++i) af[i] = *(const short8*)(Ar + bo + 1024 + i*512);
#pragma unroll
    for (int i = 0; i < 2; ++i)
#pragma unroll
      for (int j = 0; j < 4; ++j)
        acc[2+i][j] = __builtin_amdgcn_mfma_f32_16x16x32_bf16(af[i], bfr[j], acc[2+i][j], 0, 0, 0);
    __builtin_amdgcn_s_setprio(0);
    if (t + 4 <= nt)      VMW(8);
    else if (t + 3 == nt) VMW(4);
    else if (t + 2 == nt) VMW(0);
    __builtin_amdgcn_s_barrier();
  }

  const int mB = m0 + wr*64 + quad*4;
  const int nB = n0 + wc*64 + ln;
#pragma unroll
  for (int i = 0; i < 4; ++i)
#pragma unroll
    for (int r = 0; r < 4; ++r)
#pragma unroll
      for (int j = 0; j < 4; ++j)
        gemm_epi<EPI>(Cout, mB + i*16 + r, nB + j*16, N, m_off, acc[i][j][r], e0, e1, e2);
}

// ---------------- RoPE + repack; q pre-scaled by 1/sqrt(D)=0.125 ----------------
// kp/vt tiles carry the quarter-wave bank swizzle: 16B slot s within row r is
// stored at s ^ ((r>>1)&3). attn reads with the matching XOR.
__global__ __launch_bounds__(256) void rope_pack(
    const u16* __restrict__ qkv, const float* __restrict__ cosT,
    const float* __restrict__ sinT, u16* __restrict__ qp,
    u16* __restrict__ kp, u16* __restrict__ vt){
  int blk = blockIdx.x;                       // B*H*(L/64) = 2048
  int lt = blk & 15, h = (blk >> 4) & 15, b = blk >> 8;
  int l0 = lt*64;
  int bh = b*16 + h;
  __shared__ u16 vl[64][68];
  int tid = threadIdx.x;
  size_t tile_base = (size_t)bh*65536 + (size_t)lt*4096;
#pragma unroll 4
  for (int it = 0; it < 16; ++it){
    int idx = it*256 + tid;
    int r = idx >> 6, d = idx & 63;
    int t = b*1024 + l0 + r;
    int pos = l0 + r;
    const u16* row = qkv + (size_t)t*3072 + h*64;
    float qv = bf2f(row[d]), kv = bf2f(row[1024+d]);
    float qo, ko;
    if (d < 32){
      float cs = cosT[pos*32 + d], sn = sinT[pos*32 + d];
      qo = qv*cs - bf2f(row[d+32])*sn;
      ko = kv*cs - bf2f(row[1024+d+32])*sn;
    } else {
      int dd = d - 32;
      float cs = cosT[pos*32 + dd], sn = sinT[pos*32 + dd];
      qo = qv*cs + bf2f(row[d-32])*sn;
      ko = kv*cs + bf2f(row[1024+d-32])*sn;
    }
    qp[((size_t)bh*1024 + l0 + r)*64 + d] = f2bf(qo*0.125f);
    int ksl = ((d&31) >> 3) ^ ((r >> 1) & 3);
    kp[tile_base + (d>>5)*2048 + r*32 + (ksl<<3) + (d&7)] = f2bf(ko);
    vl[d][r] = row[2048 + d];
  }
  __syncthreads();
#pragma unroll 4
  for (int it = 0; it < 16; ++it){
    int idx = it*256 + tid;
    int d = idx >> 6, cc = idx & 63;
    int vsl = ((cc&31) >> 3) ^ ((d >> 1) & 3);
    vt[tile_base + (cc>>5)*2048 + d*32 + (vsl<<3) + (cc&7)] = vl[d][cc];
  }
}

// ---------------- flash attention v4: dbuf K/V, counted vmcnt, swizzled reads,
//                  XCD-local bh mapping, defer-max rescale ----------------
__global__ __launch_bounds__(256) void attn_kernel(
    const u16* __restrict__ qp, const u16* __restrict__ kp,
    const u16* __restrict__ vtp, u16* __restrict__ ao){
  __shared__ u16 Kb[2][4096];   // [dhalf][key64][32], swizzled slots
  __shared__ u16 Vb[2][4096];   // [khalf][d64][key32], swizzled slots
  int tid = threadIdx.x, w = tid >> 6, lane = tid & 63;
  int quad = lane >> 4, ln = lane & 15;
  // same-bh blocks share blockIdx%8 -> same XCD -> K/V L2-local
  int bh = blockIdx.x & 127, qb = blockIdx.x >> 7;
  int h = bh & 15, b = bh >> 4;
  const u16* Q  = qp  + ((size_t)bh*1024 + qb*64 + w*16)*64;
  const u16* Kg = kp  + (size_t)bh*65536 + lane*8;
  const u16* Vg = vtp + (size_t)bh*65536 + lane*8;
  short8 qf0 = *(const short8*)(Q + ln*64 + quad*8);       // B[n=ln][k=quad*8+j]
  short8 qf1 = *(const short8*)(Q + ln*64 + 32 + quad*8);
  f32x4 o[4] = {};
  float m = -3e38f, l = 0.f;
  const int rsw = (quad ^ ((ln >> 1) & 3))*8;

  // stage tile 0
  async16(Kg + (w*2+0)*512, Kb[0] + (w*2+0)*512);
  async16(Kg + (w*2+1)*512, Kb[0] + (w*2+1)*512);
  async16(Vg + (w*2+0)*512, Vb[0] + (w*2+0)*512);
  async16(Vg + (w*2+1)*512, Vb[0] + (w*2+1)*512);

  for (int kt = 0; kt < 16; ++kt){
    const int cur = kt & 1;
    if (kt < 15){
      const u16* ktg = Kg + (kt+1)*4096;
      const u16* vtg = Vg + (kt+1)*4096;
      async16(ktg + (w*2+0)*512, Kb[cur^1] + (w*2+0)*512);
      async16(ktg + (w*2+1)*512, Kb[cur^1] + (w*2+1)*512);
      async16(vtg + (w*2+0)*512, Vb[cur^1] + (w*2+0)*512);
      async16(vtg + (w*2+1)*512, Vb[cur^1] + (w*2+1)*512);
      VMW(4);                      // wait tile kt only; kt+1 stays in flight
    } else {
      VMW(0);
    }
    __builtin_amdgcn_s_barrier();
    // ---- S^T = K·Q^T ----
    f32x4 zz = {0.f, 0.f, 0.f, 0.f};
    f32x4 st[4];
    __builtin_amdgcn_s_setprio(1);
#pragma unroll
    for (int c = 0; c < 4; ++c){
      short8 k0 = *(const short8*)(Kb[cur] +        (c*16 + ln)*32 + rsw);
      short8 k1 = *(const short8*)(Kb[cur] + 2048 + (c*16 + ln)*32 + rsw);
      st[c] = __builtin_amdgcn_mfma_f32_16x16x32_bf16(k0, qf0, zz, 0,0,0);
      st[c] = __builtin_amdgcn_mfma_f32_16x16x32_bf16(k1, qf1, st[c], 0,0,0);
    }
    __builtin_amdgcn_s_setprio(0);
    short8 va[4][2];
#pragma unroll
    for (int dc = 0; dc < 4; ++dc)
#pragma unroll
      for (int kh = 0; kh < 2; ++kh)
        va[dc][kh] = *(const short8*)(Vb[cur] + kh*2048 + (dc*16 + ln)*32 + rsw);
    // ---- softmax (per-lane: qrow = ln) ----
    float mx = st[0][0];
#pragma unroll
    for (int c = 0; c < 4; ++c)
#pragma unroll
      for (int r = 0; r < 4; ++r) mx = fmaxf(mx, st[c][r]);
    mx = fmaxf(mx, __shfl_xor(mx, 16));
    mx = fmaxf(mx, __shfl_xor(mx, 32));
    // defer-max: only rescale when the running max actually grew (> +8)
    if (__any(mx > m + 8.f)){
      float mn = fmaxf(m, mx);
      float alpha = __expf(m - mn);
      m = mn;
      l *= alpha;
#pragma unroll
      for (int dc = 0; dc < 4; ++dc)
#pragma unroll
        for (int r = 0; r < 4; ++r) o[dc][r] *= alpha;
    }
    float p[4][4];
#pragma unroll
    for (int c = 0; c < 4; ++c)
#pragma unroll
      for (int r = 0; r < 4; ++r) p[c][r] = __expf(st[c][r] - m);
    float sum = ((p[0][0]+p[0][1]) + (p[0][2]+p[0][3])) + ((p[1][0]+p[1][1]) + (p[1][2]+p[1][3]))
              + ((p[2][0]+p[2][1]) + (p[2][2]+p[2][3])) + ((p[3][0]+p[3][1]) + (p[3][2]+p[3][3]));
    sum += __shfl_xor(sum, 16);
    sum += __shfl_xor(sum, 32);
    l += sum;
    unsigned pc[4][2];
#pragma unroll
    for (int c = 0; c < 4; ++c){
      pc[c][0] = packbf(p[c][0], p[c][1]);
      pc[c][1] = packbf(p[c][2], p[c][3]);
    }
    const int sA = ((quad & 1)*2)*16 + ln;
    const int sB = sA + 16;
    const bool hi = quad >= 2;
#pragma unroll
    for (int kh = 0; kh < 2; ++kh){
      unsigned a0 = (unsigned)__shfl((int)pc[2*kh][0],   sA);
      unsigned b0 = (unsigned)__shfl((int)pc[2*kh+1][0], sA);
      unsigned a1 = (unsigned)__shfl((int)pc[2*kh][1],   sA);
      unsigned b1 = (unsigned)__shfl((int)pc[2*kh+1][1], sA);
      unsigned a2 = (unsigned)__shfl((int)pc[2*kh][0],   sB);
      unsigned b2 = (unsigned)__shfl((int)pc[2*kh+1][0], sB);
      unsigned a3 = (unsigned)__shfl((int)pc[2*kh][1],   sB);
      unsigned b3 = (unsigned)__shfl((int)pc[2*kh+1][1], sB);
      uint4v u = { hi ? b0 : a0, hi ? b1 : a1, hi ? b2 : a2, hi ? b3 : a3 };
      short8 pfrag = __builtin_bit_cast(short8, u);
      __builtin_amdgcn_s_setprio(1);
#pragma unroll
      for (int dc = 0; dc < 4; ++dc)
        o[dc] = __builtin_amdgcn_mfma_f32_16x16x32_bf16(va[dc][kh], pfrag, o[dc], 0,0,0);
      __builtin_amdgcn_s_setprio(0);
    }
    __builtin_amdgcn_s_barrier();   // all waves done reading buf cur
  }
  float rl = 1.f / l;
  size_t orow = ((size_t)b*1024 + qb*64 + w*16 + ln)*1024 + h*64;
#pragma unroll
  for (int dc = 0; dc < 4; ++dc)
#pragma unroll
    for (int r = 0; r < 4; ++r)
      ao[orow + dc*16 + quad*4 + r] = f2bf(o[dc][r] * rl);
}

// ---------------- launch ----------------
extern "C" void kernel_launch(void* const* d_in, const int* in_sizes, int n_in,
                              void* d_out, int out_size, void* d_ws, size_t ws_size,
                              hipStream_t stream){
  const float* x    = (const float*)d_in[0];
  const float* cosT = (const float*)d_in[3];
  const float* sinT = (const float*)d_in[4];
  const float* c    = (const float*)d_in[6];
  const float* ln1w = (const float*)d_in[7];
  const float* Wq   = (const float*)d_in[8];
  const float* Wk   = (const float*)d_in[9];
  const float* Wv   = (const float*)d_in[10];
  const float* Wo   = (const float*)d_in[11];
  const float* ln2w = (const float*)d_in[12];
  const float* W1   = (const float*)d_in[13];
  const float* b1   = (const float*)d_in[14];
  const float* W2   = (const float*)d_in[15];
  const float* b2   = (const float*)d_in[16];
  const float* adaW = (const float*)d_in[17];
  const float* adaB = (const float*)d_in[18];

  char* ws = (char*)d_ws;
  float* ada  = (float*)(ws);
  u16* wqkvt  = (u16*)  (ws + 262144);
  u16* wot    = (u16*)  (ws + 6553600);
  u16* w1t    = (u16*)  (ws + 8650752);
  u16* w2t    = (u16*)  (ws + 17039360);
  u16* h      = (u16*)  (ws + 25427968);
  u16* qp     = (u16*)  (ws + 25427968);
  u16* h2     = (u16*)  (ws + 25427968);
  u16* qkv    = (u16*)  (ws + 42205184);
  u16* attnb  = (u16*)  (ws + 42205184);
  float* xmid = (float*)(ws + 58982400);
  float* adaP = (float*)(ws + 92536832);   // 1.5 MB, dead before rope_pack
  u16* kp     = (u16*)  (ws + 92536832);
  u16* vt     = (u16*)  (ws + 109314048);
  u16* hid    = (u16*)  (ws + 92536832);
  u16* hidF   = (u16*)  (ws + 126091264);
  float* out  = (float*)d_out;
  const bool bigws = ws_size >= (size_t)193200128;

  ada_partial<<<dim3(24,8,8), 256, 0, stream>>>(c, adaW, adaP);
  ada_reduce<<<192, 256, 0, stream>>>(adaP, adaB, ada);
  transpose_cast<<<dim3(16,16), 256, 0, stream>>>(Wq, wqkvt,             1024, 1024);
  transpose_cast<<<dim3(16,16), 256, 0, stream>>>(Wk, wqkvt + 1024*1024, 1024, 1024);
  transpose_cast<<<dim3(16,16), 256, 0, stream>>>(Wv, wqkvt + 2048*1024, 1024, 1024);
  transpose_cast<<<dim3(16,16), 256, 0, stream>>>(Wo, wot,               1024, 1024);
  transpose_cast<<<dim3(64,16), 256, 0, stream>>>(W1, w1t,               1024, 4096);
  transpose_cast<<<dim3(16,64), 256, 0, stream>>>(W2, w2t,               4096, 1024);
  ln_mod<<<8192, 256, 0, stream>>>(x, h, ln1w, ada, 0, 1024);
  gemm_bt128<0><<<dim3(24,64), 256, 0, stream>>>(h, wqkvt, qkv, 8192, 3072, 1024, 0,
                                                 nullptr, nullptr, nullptr);
  rope_pack<<<2048, 256, 0, stream>>>(qkv, cosT, sinT, qp, kp, vt);
  attn_kernel<<<2048, 256, 0, stream>>>(qp, kp, vt, attnb);
  gemm_bt128<1><<<dim3(8,64), 256, 0, stream>>>(attnb, wot, xmid, 8192, 1024, 1024, 0,
                                                x, ada, nullptr);
  ln_mod<<<8192, 256, 0, stream>>>(xmid, h2, ln2w, ada, 3072, 4096);
  if (bigws){
    gemm_bt<2><<<dim3(16,32), 512, 0, stream>>>(h2, w1t, hidF, 8192, 4096, 1024, 0,
                                                b1, nullptr, nullptr);
    gemm_bt128<3><<<dim3(8,64), 256, 0, stream>>>(hidF, w2t, out, 8192, 1024, 4096, 0,
                                                  b2, ada, xmid);
  } else {
    for (int cch = 0; cch < 2; ++cch){
      const size_t mo = (size_t)cch*4096;
      gemm_bt<2><<<dim3(16,16), 512, 0, stream>>>(h2 + mo*1024, w1t, hid,
                                                  4096, 4096, 1024, (int)mo,
                                                  b1, nullptr, nullptr);
      gemm_bt128<3><<<dim3(8,32), 256, 0, stream>>>(hid, w2t, out + mo*1024,
                                                    4096, 1024, 4096, (int)mo,
                                                    b2, ada, xmid + mo*1024);
    }
  }
}

// Round 9
// 581.846 us; speedup vs baseline: 1.0133x; 1.0133x over previous
//
#include <hip/hip_runtime.h>

typedef unsigned short u16;
typedef __attribute__((ext_vector_type(8))) short short8;
typedef __attribute__((ext_vector_type(4))) float f32x4;
typedef __attribute__((ext_vector_type(4))) unsigned uint4v;

__device__ __forceinline__ float bf2f(u16 u){
  unsigned v = ((unsigned)u) << 16;
  return __builtin_bit_cast(float, v);
}
__device__ __forceinline__ u16 f2bf(float f){
  unsigned u = __builtin_bit_cast(unsigned, f);
  u += 0x7fff + ((u >> 16) & 1);   // RNE
  return (u16)(u >> 16);
}
__device__ __forceinline__ unsigned packbf(float lo, float hi){
  return ((unsigned)f2bf(hi) << 16) | (unsigned)f2bf(lo);
}
__device__ __forceinline__ void async16(const void* g, void* l){
  __builtin_amdgcn_global_load_lds((const __attribute__((address_space(1))) void*)g,
                                   (__attribute__((address_space(3))) void*)l, 16, 0, 0);
}
#define VMW(n) asm volatile("s_waitcnt vmcnt(" #n ")" ::: "memory")

// ---------------- ada partials ----------------
__global__ __launch_bounds__(256) void ada_partial(
    const float* __restrict__ c, const float* __restrict__ aw,
    float* __restrict__ part){
  int n  = blockIdx.x*256 + threadIdx.x;    // 24 x-blocks
  int b  = blockIdx.y;                      // 8
  int kc = blockIdx.z;                      // 8
  const float* cr  = c + b*1024 + kc*128;
  const float* awp = aw + (size_t)(kc*128)*6144 + n;
  float acc = 0.f;
#pragma unroll 8
  for (int k = 0; k < 128; ++k)
    acc += cr[k] * awp[(size_t)k*6144];
  part[(size_t)(kc*8 + b)*6144 + n] = acc;
}

// ---------------- ada = sum_kc part + ab ----------------
__global__ __launch_bounds__(256) void ada_reduce(
    const float* __restrict__ part, const float* __restrict__ ab,
    float* __restrict__ ada){
  int idx = blockIdx.x*256 + threadIdx.x;   // 192 blocks
  int n = idx % 6144;
  float acc = ab[n];
#pragma unroll
  for (int kc = 0; kc < 8; ++kc)
    acc += part[(size_t)kc*49152 + idx];
  ada[idx] = acc;
}

// ---------------- transpose + cast f32[K][N] -> bf16[N][K] ----------------
__global__ __launch_bounds__(256) void transpose_cast(
    const float* __restrict__ src, u16* __restrict__ dst, int K, int N){
  __shared__ float t[64][65];
  int n0 = blockIdx.x*64, k0 = blockIdx.y*64;
  int tid = threadIdx.x;
  int cc = tid & 63, r4 = tid >> 6;
#pragma unroll 4
  for (int it = 0; it < 16; ++it){
    int r = it*4 + r4;
    t[r][cc] = src[(size_t)(k0 + r)*N + n0 + cc];
  }
  __syncthreads();
#pragma unroll 4
  for (int it = 0; it < 16; ++it){
    int r = it*4 + r4;
    dst[(size_t)(n0 + r)*K + k0 + cc] = f2bf(t[cc][r]);
  }
}

// ---------------- LayerNorm + adaLN modulate -> bf16 ----------------
__global__ __launch_bounds__(256) void ln_mod(
    const float* __restrict__ x, u16* __restrict__ out,
    const float* __restrict__ w, const float* __restrict__ ada,
    int shift_off, int scale_off){
  int t = blockIdx.x, tid = threadIdx.x;
  const float* xr = x + (size_t)t*1024;
  float v[4]; float s = 0.f, ss = 0.f;
#pragma unroll
  for (int i = 0; i < 4; ++i){ v[i] = xr[tid + i*256]; s += v[i]; ss += v[i]*v[i]; }
  for (int d = 1; d < 64; d <<= 1){ s += __shfl_xor(s, d); ss += __shfl_xor(ss, d); }
  __shared__ float red[8];
  int wv = tid >> 6;
  if ((tid & 63) == 0){ red[wv] = s; red[4+wv] = ss; }
  __syncthreads();
  s = red[0]+red[1]+red[2]+red[3];
  ss = red[4]+red[5]+red[6]+red[7];
  float mu = s * (1.f/1024.f);
  float var = ss * (1.f/1024.f) - mu*mu;
  float rs = rsqrtf(var + 1e-5f);
  int b = t >> 10;
  const float* sh = ada + b*6144 + shift_off;
  const float* sc = ada + b*6144 + scale_off;
#pragma unroll
  for (int i = 0; i < 4; ++i){
    int cidx = tid + i*256;
    float hh = (v[i]-mu)*rs*w[cidx]*(1.f + sc[cidx]) + sh[cidx];
    out[(size_t)t*1024 + cidx] = f2bf(hh);
  }
}

// Epilogue shared by both GEMM variants.
template<int EPI>
__device__ __forceinline__ void gemm_epi(
    void* Cout, int m, int n, int N, int m_off, float v,
    const float* e0, const float* e1, const float* e2){
  if (EPI == 0){
    ((u16*)Cout)[(size_t)m*N + n] = f2bf(v);
  } else if (EPI == 1){
    const int b = (m + m_off) >> 10;
    float g = e1[b*6144 + 2048 + n];
    ((float*)Cout)[(size_t)m*N + n] = e0[(size_t)m*N + n] + g*v;
  } else if (EPI == 2){
    float xx = v + e0[n];
    // gelu(tanh approx) = x * sigmoid(1.595769122x + 0.0713548163x^3)
    float u = xx*(1.5957691216f + 0.07135481626f*xx*xx);
    ((u16*)Cout)[(size_t)m*N + n] = f2bf(xx / (1.f + __expf(-u)));
  } else {
    const int b = (m + m_off) >> 10;
    float g = e1[b*6144 + 5120 + n];
    ((float*)Cout)[(size_t)m*N + n] = e2[(size_t)m*N + n] + g*(v + e0[n]);
  }
}

// XCD-chunked bijective remap: HW assigns XCD = linear_bid % 8 (x-fastest).
// Give XCD g a contiguous y-band (ny/8 rows) x all x, so blocks sharing an
// A-row-panel are co-resident on ONE XCD (A fetched once per L2, not 8x).
// Requires gridDim.y % 8 == 0.
__device__ __forceinline__ void xcd_remap(int& bx, int& by){
  const int nx = gridDim.x;
  const int yb = gridDim.y >> 3;
  const int bid = blockIdx.y*nx + blockIdx.x;
  const int g = bid & 7, ii = bid >> 3;
  bx = ii % nx;
  by = g*yb + ii/nx;
}

// ---------------- GEMM 256x256, BK=32, 2-deep dbuf (64 KiB -> 2 blocks/CU),
// one barrier per K-step, swizzled LDS, XCD remap.
// Occupancy: LDS 2x64=128<=160 KiB and VGPR ~96<=128 give 16 waves/CU =
// 4 waves/SIMD — the co-resident block covers this block's VMW(0) drain.
// launch_bounds MUST stay (512,2): (512,4) forces a 128-VGPR cap -> acc spills
// (round-6: 2.9 GB scratch, 6x slower). If counters show VGPR>128, occupancy
// fell back to 1 block/CU.
// Hazard ledger (one barrier): stage(t) writes buf[(t+1)&1], last read at step
// t-1, ordered by end-of-(t-1) barrier; reads of buf[t&1] need tile t landed =
// end-of-(t-1) VMW(0)+barrier; within-wave ds_read->MFMA = compiler lgkmcnt.
template<int EPI>
__global__ __launch_bounds__(512, 2) void gemm_bt(
    const u16* __restrict__ A, const u16* __restrict__ Bt,
    void* __restrict__ Cout, int M, int N, int K, int m_off,
    const float* __restrict__ e0, const float* __restrict__ e1,
    const float* __restrict__ e2){
  __shared__ u16 lds[32768];               // 64 KiB: 2 bufs x (A 256x32 + B 256x32)
  const int tid = threadIdx.x;
  const int wv = tid >> 6, lane = tid & 63;
  const int quad = lane >> 4, ln = lane & 15;
  const int wr = wv >> 2, wc = wv & 3;
  int bx, by; xcd_remap(bx, by);
  const int n0 = bx*256, m0 = by*256;
  const int nt = K >> 5;

  const int swslot = (lane & 3) ^ ((lane >> 3) & 3);
  const u16* Ap = A  + (size_t)(m0 + wv*16 + (lane>>2))*K + swslot*8;
  const u16* Bp = Bt + (size_t)(n0 + wv*16 + (lane>>2))*K + swslot*8;
  const size_t hstep = (size_t)128*K;
  u16* lw = lds + wv*512;                  // wave-uniform LDS slice base

  f32x4 acc[8][4] = {};

  // prologue: stage tile 0
  async16(Ap,         lw);
  async16(Ap + hstep, lw + 4096);
  async16(Bp,         lw + 8192);
  async16(Bp + hstep, lw + 12288);
  VMW(0);
  __builtin_amdgcn_s_barrier();

  const int rsw = (quad ^ ((ln >> 1) & 3))*8;
  const u16* Ar = lds + (wr*128 + ln)*32 + rsw;
  const u16* Br = lds + 8192 + (wc*64 + ln)*32 + rsw;

  for (int t = 0; t < nt; ++t){
    const int bo = (t & 1)*16384;
    short8 bfr[4], af[4];
#pragma unroll
    for (int j = 0; j < 4; ++j) bfr[j] = *(const short8*)(Br + bo + j*512);
#pragma unroll
    for (int i = 0; i < 4; ++i) af[i]  = *(const short8*)(Ar + bo + i*512);
    if (t + 1 < nt){
      u16* d = lw + ((t+1)&1)*16384;
      async16(Ap + (size_t)(t+1)*32,         d);
      async16(Ap + hstep + (size_t)(t+1)*32, d + 4096);
      async16(Bp + (size_t)(t+1)*32,         d + 8192);
      async16(Bp + hstep + (size_t)(t+1)*32, d + 12288);
    }
    __builtin_amdgcn_s_setprio(1);
#pragma unroll
    for (int i = 0; i < 4; ++i)
#pragma unroll
      for (int j = 0; j < 4; ++j)
        acc[i][j] = __builtin_amdgcn_mfma_f32_16x16x32_bf16(af[i], bfr[j], acc[i][j], 0, 0, 0);
#pragma unroll
    for (int i = 0; i < 4; ++i) af[i] = *(const short8*)(Ar + bo + 2048 + i*512);
#pragma unroll
    for (int i = 0; i < 4; ++i)
#pragma unroll
      for (int j = 0; j < 4; ++j)
        acc[4+i][j] = __builtin_amdgcn_mfma_f32_16x16x32_bf16(af[i], bfr[j], acc[4+i][j], 0, 0, 0);
    __builtin_amdgcn_s_setprio(0);
    VMW(0);                                 // tile t+1 landed; other block covers
    __builtin_amdgcn_s_barrier();
  }

  const int mB = m0 + wr*128 + quad*4;
  const int nB = n0 + wc*64 + ln;
#pragma unroll
  for (int i = 0; i < 8; ++i)
#pragma unroll
    for (int r = 0; r < 4; ++r)
#pragma unroll
      for (int j = 0; j < 4; ++j)
        gemm_epi<EPI>(Cout, mB + i*16 + r, nB + j*16, N, m_off, acc[i][j][r], e0, e1, e2);
}

// ---------------- GEMM 128x128, BK=32, 4-deep ring, counted vmcnt, swizzled LDS,
// one barrier per K-step. LDS is 64 KiB -> 2 blocks/CU (VGPR 104 also caps at
// 16 waves/CU, so 2 blocks is the structural max for this tile).
template<int EPI>
__global__ __launch_bounds__(256, 4) void gemm_bt128(
    const u16* __restrict__ A, const u16* __restrict__ Bt,
    void* __restrict__ Cout, int M, int N, int K, int m_off,
    const float* __restrict__ e0, const float* __restrict__ e1,
    const float* __restrict__ e2){
  __shared__ u16 lds[32768];               // 64 KiB: 4 bufs x (A 128x32 + B 128x32)
  const int tid = threadIdx.x;
  const int wv = tid >> 6, lane = tid & 63;
  const int quad = lane >> 4, ln = lane & 15;
  const int wr = wv >> 1, wc = wv & 1;
  int bx, by; xcd_remap(bx, by);
  const int n0 = bx*128, m0 = by*128;
  const int nt = K >> 5;

  const int swslot = (lane & 3) ^ ((lane >> 3) & 3);
  const u16* Ap = A  + (size_t)(m0 + wv*16 + (lane>>2))*K + swslot*8;
  const u16* Bp = Bt + (size_t)(n0 + wv*16 + (lane>>2))*K + swslot*8;
  const size_t hstep = (size_t)64*K;
  u16* lw = lds + wv*512;

  f32x4 acc[4][4] = {};

#pragma unroll
  for (int tau = 0; tau < 3; ++tau){
    u16* d = lw + tau*8192;
    async16(Ap + (size_t)tau*32,         d);
    async16(Ap + hstep + (size_t)tau*32, d + 2048);
    async16(Bp + (size_t)tau*32,         d + 4096);
    async16(Bp + hstep + (size_t)tau*32, d + 6144);
  }
  VMW(8);
  __builtin_amdgcn_s_barrier();

  const int rsw = (quad ^ ((ln >> 1) & 3))*8;
  const u16* Ar = lds + (wr*64 + ln)*32 + rsw;
  const u16* Br = lds + 4096 + (wc*64 + ln)*32 + rsw;

  for (int t = 0; t < nt; ++t){
    const int bo = (t & 3)*8192;
    short8 bfr[4], af[2];
#pragma unroll
    for (int j = 0; j < 4; ++j) bfr[j] = *(const short8*)(Br + bo + j*512);
#pragma unroll
    for (int i = 0; i < 2; ++i) af[i]  = *(const short8*)(Ar + bo + i*512);
    if (t + 3 < nt){
      u16* d = lw + ((t+3)&3)*8192;
      async16(Ap + (size_t)(t+3)*32,         d);
      async16(Ap + hstep + (size_t)(t+3)*32, d + 2048);
      async16(Bp + (size_t)(t+3)*32,         d + 4096);
      async16(Bp + hstep + (size_t)(t+3)*32, d + 6144);
    }
    __builtin_amdgcn_s_setprio(1);
#pragma unroll
    for (int i = 0; i < 2; ++i)
#pragma unroll
      for (int j = 0; j < 4; ++j)
        acc[i][j] = __builtin_amdgcn_mfma_f32_16x16x32_bf16(af[i], bfr[j], acc[i][j], 0, 0, 0);
#pragma unroll
    for (int i = 0; i < 2; ++i) af[i] = *(const short8*)(Ar + bo + 1024 + i*512);
#pragma unroll
    for (int i = 0; i < 2; ++i)
#pragma unroll
      for (int j = 0; j < 4; ++j)
        acc[2+i][j] = __builtin_amdgcn_mfma_f32_16x16x32_bf16(af[i], bfr[j], acc[2+i][j], 0, 0, 0);
    __builtin_amdgcn_s_setprio(0);
    if (t + 4 <= nt)      VMW(8);
    else if (t + 3 == nt) VMW(4);
    else if (t + 2 == nt) VMW(0);
    __builtin_amdgcn_s_barrier();
  }

  const int mB = m0 + wr*64 + quad*4;
  const int nB = n0 + wc*64 + ln;
#pragma unroll
  for (int i = 0; i < 4; ++i)
#pragma unroll
    for (int r = 0; r < 4; ++r)
#pragma unroll
      for (int j = 0; j < 4; ++j)
        gemm_epi<EPI>(Cout, mB + i*16 + r, nB + j*16, N, m_off, acc[i][j][r], e0, e1, e2);
}

// ---------------- RoPE + repack; q pre-scaled by 1/sqrt(D)=0.125 ----------------
// kp/vt tiles carry the quarter-wave bank swizzle: 16B slot s within row r is
// stored at s ^ ((r>>1)&3). attn reads with the matching XOR.
__global__ __launch_bounds__(256) void rope_pack(
    const u16* __restrict__ qkv, const float* __restrict__ cosT,
    const float* __restrict__ sinT, u16* __restrict__ qp,
    u16* __restrict__ kp, u16* __restrict__ vt){
  int blk = blockIdx.x;                       // B*H*(L/64) = 2048
  int lt = blk & 15, h = (blk >> 4) & 15, b = blk >> 8;
  int l0 = lt*64;
  int bh = b*16 + h;
  __shared__ u16 vl[64][68];
  int tid = threadIdx.x;
  size_t tile_base = (size_t)bh*65536 + (size_t)lt*4096;
#pragma unroll 4
  for (int it = 0; it < 16; ++it){
    int idx = it*256 + tid;
    int r = idx >> 6, d = idx & 63;
    int t = b*1024 + l0 + r;
    int pos = l0 + r;
    const u16* row = qkv + (size_t)t*3072 + h*64;
    float qv = bf2f(row[d]), kv = bf2f(row[1024+d]);
    float qo, ko;
    if (d < 32){
      float cs = cosT[pos*32 + d], sn = sinT[pos*32 + d];
      qo = qv*cs - bf2f(row[d+32])*sn;
      ko = kv*cs - bf2f(row[1024+d+32])*sn;
    } else {
      int dd = d - 32;
      float cs = cosT[pos*32 + dd], sn = sinT[pos*32 + dd];
      qo = qv*cs + bf2f(row[d-32])*sn;
      ko = kv*cs + bf2f(row[1024+d-32])*sn;
    }
    qp[((size_t)bh*1024 + l0 + r)*64 + d] = f2bf(qo*0.125f);
    int ksl = ((d&31) >> 3) ^ ((r >> 1) & 3);
    kp[tile_base + (d>>5)*2048 + r*32 + (ksl<<3) + (d&7)] = f2bf(ko);
    vl[d][r] = row[2048 + d];
  }
  __syncthreads();
#pragma unroll 4
  for (int it = 0; it < 16; ++it){
    int idx = it*256 + tid;
    int d = idx >> 6, cc = idx & 63;
    int vsl = ((cc&31) >> 3) ^ ((d >> 1) & 3);
    vt[tile_base + (cc>>5)*2048 + d*32 + (vsl<<3) + (cc&7)] = vl[d][cc];
  }
}

// ---------------- flash attention v4: dbuf K/V, counted vmcnt, swizzled reads,
//                  XCD-local bh mapping, defer-max rescale ----------------
__global__ __launch_bounds__(256) void attn_kernel(
    const u16* __restrict__ qp, const u16* __restrict__ kp,
    const u16* __restrict__ vtp, u16* __restrict__ ao){
  __shared__ u16 Kb[2][4096];   // [dhalf][key64][32], swizzled slots
  __shared__ u16 Vb[2][4096];   // [khalf][d64][key32], swizzled slots
  int tid = threadIdx.x, w = tid >> 6, lane = tid & 63;
  int quad = lane >> 4, ln = lane & 15;
  // same-bh blocks share blockIdx%8 -> same XCD -> K/V L2-local
  int bh = blockIdx.x & 127, qb = blockIdx.x >> 7;
  int h = bh & 15, b = bh >> 4;
  const u16* Q  = qp  + ((size_t)bh*1024 + qb*64 + w*16)*64;
  const u16* Kg = kp  + (size_t)bh*65536 + lane*8;
  const u16* Vg = vtp + (size_t)bh*65536 + lane*8;
  short8 qf0 = *(const short8*)(Q + ln*64 + quad*8);       // B[n=ln][k=quad*8+j]
  short8 qf1 = *(const short8*)(Q + ln*64 + 32 + quad*8);
  f32x4 o[4] = {};
  float m = -3e38f, l = 0.f;
  const int rsw = (quad ^ ((ln >> 1) & 3))*8;

  // stage tile 0
  async16(Kg + (w*2+0)*512, Kb[0] + (w*2+0)*512);
  async16(Kg + (w*2+1)*512, Kb[0] + (w*2+1)*512);
  async16(Vg + (w*2+0)*512, Vb[0] + (w*2+0)*512);
  async16(Vg + (w*2+1)*512, Vb[0] + (w*2+1)*512);

  for (int kt = 0; kt < 16; ++kt){
    const int cur = kt & 1;
    if (kt < 15){
      const u16* ktg = Kg + (kt+1)*4096;
      const u16* vtg = Vg + (kt+1)*4096;
      async16(ktg + (w*2+0)*512, Kb[cur^1] + (w*2+0)*512);
      async16(ktg + (w*2+1)*512, Kb[cur^1] + (w*2+1)*512);
      async16(vtg + (w*2+0)*512, Vb[cur^1] + (w*2+0)*512);
      async16(vtg + (w*2+1)*512, Vb[cur^1] + (w*2+1)*512);
      VMW(4);                      // wait tile kt only; kt+1 stays in flight
    } else {
      VMW(0);
    }
    __builtin_amdgcn_s_barrier();
    // ---- S^T = K·Q^T ----
    f32x4 zz = {0.f, 0.f, 0.f, 0.f};
    f32x4 st[4];
    __builtin_amdgcn_s_setprio(1);
#pragma unroll
    for (int c = 0; c < 4; ++c){
      short8 k0 = *(const short8*)(Kb[cur] +        (c*16 + ln)*32 + rsw);
      short8 k1 = *(const short8*)(Kb[cur] + 2048 + (c*16 + ln)*32 + rsw);
      st[c] = __builtin_amdgcn_mfma_f32_16x16x32_bf16(k0, qf0, zz, 0,0,0);
      st[c] = __builtin_amdgcn_mfma_f32_16x16x32_bf16(k1, qf1, st[c], 0,0,0);
    }
    __builtin_amdgcn_s_setprio(0);
    short8 va[4][2];
#pragma unroll
    for (int dc = 0; dc < 4; ++dc)
#pragma unroll
      for (int kh = 0; kh < 2; ++kh)
        va[dc][kh] = *(const short8*)(Vb[cur] + kh*2048 + (dc*16 + ln)*32 + rsw);
    // ---- softmax (per-lane: qrow = ln) ----
    float mx = st[0][0];
#pragma unroll
    for (int c = 0; c < 4; ++c)
#pragma unroll
      for (int r = 0; r < 4; ++r) mx = fmaxf(mx, st[c][r]);
    mx = fmaxf(mx, __shfl_xor(mx, 16));
    mx = fmaxf(mx, __shfl_xor(mx, 32));
    // defer-max: only rescale when the running max actually grew (> +8)
    if (__any(mx > m + 8.f)){
      float mn = fmaxf(m, mx);
      float alpha = __expf(m - mn);
      m = mn;
      l *= alpha;
#pragma unroll
      for (int dc = 0; dc < 4; ++dc)
#pragma unroll
        for (int r = 0; r < 4; ++r) o[dc][r] *= alpha;
    }
    float p[4][4];
#pragma unroll
    for (int c = 0; c < 4; ++c)
#pragma unroll
      for (int r = 0; r < 4; ++r) p[c][r] = __expf(st[c][r] - m);
    float sum = ((p[0][0]+p[0][1]) + (p[0][2]+p[0][3])) + ((p[1][0]+p[1][1]) + (p[1][2]+p[1][3]))
              + ((p[2][0]+p[2][1]) + (p[2][2]+p[2][3])) + ((p[3][0]+p[3][1]) + (p[3][2]+p[3][3]));
    sum += __shfl_xor(sum, 16);
    sum += __shfl_xor(sum, 32);
    l += sum;
    unsigned pc[4][2];
#pragma unroll
    for (int c = 0; c < 4; ++c){
      pc[c][0] = packbf(p[c][0], p[c][1]);
      pc[c][1] = packbf(p[c][2], p[c][3]);
    }
    const int sA = ((quad & 1)*2)*16 + ln;
    const int sB = sA + 16;
    const bool hi = quad >= 2;
#pragma unroll
    for (int kh = 0; kh < 2; ++kh){
      unsigned a0 = (unsigned)__shfl((int)pc[2*kh][0],   sA);
      unsigned b0 = (unsigned)__shfl((int)pc[2*kh+1][0], sA);
      unsigned a1 = (unsigned)__shfl((int)pc[2*kh][1],   sA);
      unsigned b1 = (unsigned)__shfl((int)pc[2*kh+1][1], sA);
      unsigned a2 = (unsigned)__shfl((int)pc[2*kh][0],   sB);
      unsigned b2 = (unsigned)__shfl((int)pc[2*kh+1][0], sB);
      unsigned a3 = (unsigned)__shfl((int)pc[2*kh][1],   sB);
      unsigned b3 = (unsigned)__shfl((int)pc[2*kh+1][1], sB);
      uint4v u = { hi ? b0 : a0, hi ? b1 : a1, hi ? b2 : a2, hi ? b3 : a3 };
      short8 pfrag = __builtin_bit_cast(short8, u);
      __builtin_amdgcn_s_setprio(1);
#pragma unroll
      for (int dc = 0; dc < 4; ++dc)
        o[dc] = __builtin_amdgcn_mfma_f32_16x16x32_bf16(va[dc][kh], pfrag, o[dc], 0,0,0);
      __builtin_amdgcn_s_setprio(0);
    }
    __builtin_amdgcn_s_barrier();   // all waves done reading buf cur
  }
  float rl = 1.f / l;
  size_t orow = ((size_t)b*1024 + qb*64 + w*16 + ln)*1024 + h*64;
#pragma unroll
  for (int dc = 0; dc < 4; ++dc)
#pragma unroll
    for (int r = 0; r < 4; ++r)
      ao[orow + dc*16 + quad*4 + r] = f2bf(o[dc][r] * rl);
}

// ---------------- launch ----------------
extern "C" void kernel_launch(void* const* d_in, const int* in_sizes, int n_in,
                              void* d_out, int out_size, void* d_ws, size_t ws_size,
                              hipStream_t stream){
  const float* x    = (const float*)d_in[0];
  const float* cosT = (const float*)d_in[3];
  const float* sinT = (const float*)d_in[4];
  const float* c    = (const float*)d_in[6];
  const float* ln1w = (const float*)d_in[7];
  const float* Wq   = (const float*)d_in[8];
  const float* Wk   = (const float*)d_in[9];
  const float* Wv   = (const float*)d_in[10];
  const float* Wo   = (const float*)d_in[11];
  const float* ln2w = (const float*)d_in[12];
  const float* W1   = (const float*)d_in[13];
  const float* b1   = (const float*)d_in[14];
  const float* W2   = (const float*)d_in[15];
  const float* b2   = (const float*)d_in[16];
  const float* adaW = (const float*)d_in[17];
  const float* adaB = (const float*)d_in[18];

  char* ws = (char*)d_ws;
  float* ada  = (float*)(ws);
  u16* wqkvt  = (u16*)  (ws + 262144);
  u16* wot    = (u16*)  (ws + 6553600);
  u16* w1t    = (u16*)  (ws + 8650752);
  u16* w2t    = (u16*)  (ws + 17039360);
  u16* h      = (u16*)  (ws + 25427968);
  u16* qp     = (u16*)  (ws + 25427968);
  u16* h2     = (u16*)  (ws + 25427968);
  u16* qkv    = (u16*)  (ws + 42205184);
  u16* attnb  = (u16*)  (ws + 42205184);
  float* xmid = (float*)(ws + 58982400);
  float* adaP = (float*)(ws + 92536832);   // 1.5 MB, dead before rope_pack
  u16* kp     = (u16*)  (ws + 92536832);
  u16* vt     = (u16*)  (ws + 109314048);
  u16* hid    = (u16*)  (ws + 92536832);
  u16* hidF   = (u16*)  (ws + 126091264);
  float* out  = (float*)d_out;
  const bool bigws = ws_size >= (size_t)193200128;

  ada_partial<<<dim3(24,8,8), 256, 0, stream>>>(c, adaW, adaP);
  ada_reduce<<<192, 256, 0, stream>>>(adaP, adaB, ada);
  transpose_cast<<<dim3(16,16), 256, 0, stream>>>(Wq, wqkvt,             1024, 1024);
  transpose_cast<<<dim3(16,16), 256, 0, stream>>>(Wk, wqkvt + 1024*1024, 1024, 1024);
  transpose_cast<<<dim3(16,16), 256, 0, stream>>>(Wv, wqkvt + 2048*1024, 1024, 1024);
  transpose_cast<<<dim3(16,16), 256, 0, stream>>>(Wo, wot,               1024, 1024);
  transpose_cast<<<dim3(64,16), 256, 0, stream>>>(W1, w1t,               1024, 4096);
  transpose_cast<<<dim3(16,64), 256, 0, stream>>>(W2, w2t,               4096, 1024);
  ln_mod<<<8192, 256, 0, stream>>>(x, h, ln1w, ada, 0, 1024);
  gemm_bt128<0><<<dim3(24,64), 256, 0, stream>>>(h, wqkvt, qkv, 8192, 3072, 1024, 0,
                                                 nullptr, nullptr, nullptr);
  rope_pack<<<2048, 256, 0, stream>>>(qkv, cosT, sinT, qp, kp, vt);
  attn_kernel<<<2048, 256, 0, stream>>>(qp, kp, vt, attnb);
  gemm_bt128<1><<<dim3(8,64), 256, 0, stream>>>(attnb, wot, xmid, 8192, 1024, 1024, 0,
                                                x, ada, nullptr);
  ln_mod<<<8192, 256, 0, stream>>>(xmid, h2, ln2w, ada, 3072, 4096);
  if (bigws){
    gemm_bt<2><<<dim3(16,32), 512, 0, stream>>>(h2, w1t, hidF, 8192, 4096, 1024, 0,
                                                b1, nullptr, nullptr);
    gemm_bt128<3><<<dim3(8,64), 256, 0, stream>>>(hidF, w2t, out, 8192, 1024, 4096, 0,
                                                  b2, ada, xmid);
  } else {
    for (int cch = 0; cch < 2; ++cch){
      const size_t mo = (size_t)cch*4096;
      gemm_bt<2><<<dim3(16,16), 512, 0, stream>>>(h2 + mo*1024, w1t, hid,
                                                  4096, 4096, 1024, (int)mo,
                                                  b1, nullptr, nullptr);
      gemm_bt128<3><<<dim3(8,32), 256, 0, stream>>>(hid, w2t, out + mo*1024,
                                                    4096, 1024, 4096, (int)mo,
                                                    b2, ada, xmid + mo*1024);
    }
  }
}